// Round 9
// baseline (172.069 us; speedup 1.0000x reference)
//
#include <hip/hip_runtime.h>
#include <hip/hip_bf16.h>

typedef __bf16 bf16_t;
typedef __bf16 bf16x8 __attribute__((ext_vector_type(8)));
typedef __bf16 bf16x4 __attribute__((ext_vector_type(4)));
typedef float  f32x4  __attribute__((ext_vector_type(4)));

#define MFMA16(a, b, c) __builtin_amdgcn_mfma_f32_16x16x32_bf16((a), (b), (c), 0, 0, 0)

constexpr int E  = 1024;
constexpr int S  = 2048;
constexpr int H  = 16;
constexpr int M  = 4096;  // B*S

// ---------------------------------------------------------------------------
// async global->LDS 16B (wave-uniform LDS base + lane*16)
// ---------------------------------------------------------------------------
__device__ __forceinline__ void glds16(const bf16_t* src, bf16_t* dst) {
  __builtin_amdgcn_global_load_lds(
      (const __attribute__((address_space(1))) void*)src,
      (__attribute__((address_space(3))) void*)dst, 16, 0, 0);
}

// Stage a [ROWS x 64] bf16 tile (global row stride gld) into LDS, XOR-swizzled.
// NT = participating threads (pass a local tid in [0,NT)).
template <int ROWS, int NT>
__device__ __forceinline__ void stage_tile(const bf16_t* g, int gld,
                                           bf16_t* lds, int tid) {
  const int w = tid >> 6, l = tid & 63;
#pragma unroll
  for (int i = 0; i < ROWS * 8 / NT; ++i) {
    const int c = i * NT + w * 64 + l;
    const int row = c >> 3;
    const int gch = (c & 7) ^ (row & 7);
    glds16(g + (size_t)row * gld + gch * 8, lds + (size_t)(i * NT + w * 64) * 8);
  }
}

// Stage interleaved A-chunk c of a 256-row tile (qkv kernel helper).
__device__ __forceinline__ void stage_A_chunk(const bf16_t* g, int c,
                                              bf16_t* lds, int tid) {
  const int w = tid >> 6, l = tid & 63;
#pragma unroll
  for (int i = 0; i < 2; ++i) {
    const int gc = i * 512 + w * 64 + l;      // [0,1024)
    const int row_l = gc >> 3;                // [0,128)
    const int col8 = gc & 7;
    const int h = row_l >> 6, rr = row_l & 63;
    const int row = h * 128 + c * 64 + rr;    // LDS == global row
    const int gch = col8 ^ (row & 7);
    glds16(g + (size_t)row * E + gch * 8, lds + ((size_t)row * 8 + col8) * 8);
  }
}

// Read an 8-elem k-chunk (kc in [0,8)) of row `row` from a swizzled [R x 64] tile.
__device__ __forceinline__ bf16x8 read_frag(const bf16_t* lds, int row, int kc) {
  return *(const bf16x8*)(lds + (size_t)((row << 3) + (kc ^ (row & 7))) * 8);
}

// ---------------------------------------------------------------------------
// fused fp32->bf16 conversion for x + 4 weight matrices
// ---------------------------------------------------------------------------
__global__ void cvt_all_kernel(const float* __restrict__ x,
                               const float* __restrict__ w0, const float* __restrict__ w1,
                               const float* __restrict__ w2, const float* __restrict__ w3,
                               bf16_t* __restrict__ xb,
                               bf16_t* __restrict__ o0, bf16_t* __restrict__ o1,
                               bf16_t* __restrict__ o2, bf16_t* __restrict__ o3) {
  const int bid = blockIdx.x;
  const float* s;
  bf16_t* d;
  int idx;
  if (bid < 4096) {
    s = x; d = xb; idx = bid * 256 + threadIdx.x;
  } else {
    const int seg = (bid - 4096) >> 10;
    s = seg == 0 ? w0 : seg == 1 ? w1 : seg == 2 ? w2 : w3;
    d = seg == 0 ? o0 : seg == 1 ? o1 : seg == 2 ? o2 : o3;
    idx = ((bid - 4096) & 1023) * 256 + threadIdx.x;
  }
  float4 v = ((const float4*)s)[idx];
  bf16x4 o;
  o[0] = (bf16_t)v.x; o[1] = (bf16_t)v.y; o[2] = (bf16_t)v.z; o[3] = (bf16_t)v.w;
  ((bf16x4*)d)[idx] = o;
}

// ---------------------------------------------------------------------------
// fused QKV projection, v5 (kept): counted-vmcnt 4-phase schedule at 256x192,
// grid 16x16 = 256 blocks (all CUs). W fused [3072][1024]; Q/K row-major;
// V -> sigma-permuted VT. Q PRE-SCALED by log2(e)/8.
// ---------------------------------------------------------------------------
__global__ __launch_bounds__(512, 1) void qkv8_kernel(
    const bf16_t* __restrict__ xb, const bf16_t* __restrict__ W3,
    const float* __restrict__ bq, const float* __restrict__ bk,
    const float* __restrict__ bv, bf16_t* __restrict__ QKb,
    bf16_t* __restrict__ VT) {
  __shared__ __align__(16) bf16_t As[2][256 * 64];  // 64 KB
  __shared__ __align__(16) bf16_t Bs[2][192 * 64];  // 48 KB
  const int tid = threadIdx.x;
  const int l = tid & 63, lq = l & 15, qd = l >> 4;
  const int w = tid >> 6, wm = w >> 2, wn = w & 3;

  // XCD-aware 4x4-region swizzle over the 16x16 block grid
  const int wg = blockIdx.x;
  const int xcd = wg & 7, i5 = wg >> 3;        // i5 in [0,32)
  const int region = xcd * 2 + (i5 >> 4);      // [0,16)
  const int j = i5 & 15;
  const int bx = (region & 3) * 4 + (j & 3);   // n-tile [0,16)
  const int by = (region >> 2) * 4 + (j >> 2); // m-tile [0,16)
  const int m0 = by * 256, n0 = bx * 192;

  const bf16_t* Ag = xb + (size_t)m0 * E;
  const bf16_t* Bg = W3 + (size_t)n0 * E;

  f32x4 acc[8][3];
#pragma unroll
  for (int jj = 0; jj < 8; ++jj)
#pragma unroll
    for (int n = 0; n < 3; ++n) acc[jj][n] = (f32x4){0.f, 0.f, 0.f, 0.f};

  // prologue: B0,B1,B2,A0,A1 of tile 0 (steady-state issue order)
  stage_tile<64, 512>(Bg, E, Bs[0], tid);
  stage_tile<64, 512>(Bg + (size_t)64 * E, E, Bs[0] + 64 * 64, tid);
  stage_tile<64, 512>(Bg + (size_t)128 * E, E, Bs[0] + 128 * 64, tid);
  stage_A_chunk(Ag, 0, As[0], tid);
  stage_A_chunk(Ag, 1, As[0], tid);
  asm volatile("s_waitcnt vmcnt(2)" ::: "memory");
  __builtin_amdgcn_s_barrier();

#pragma unroll 1
  for (int g = 0; g < 16; ++g) {
    const int s = g & 1;
    const bf16_t* Al = As[s];
    const bf16_t* Bl = Bs[s];
    bf16_t* An = As[s ^ 1];
    bf16_t* Bn = Bs[s ^ 1];
    const bf16_t* Agn = Ag + (g + 1) * 64;
    const bf16_t* Bgn = Bg + (g + 1) * 64;
    const bool more = (g < 15);
    bf16x8 af[4], bfr[3];

    // ph0: A jj0-3 kk0 + B kk0; stage B0(t+1)
#pragma unroll
    for (int jj = 0; jj < 4; ++jj)
      af[jj] = read_frag(Al, wm * 128 + jj * 16 + lq, qd);
#pragma unroll
    for (int n = 0; n < 3; ++n)
      bfr[n] = read_frag(Bl, wn * 48 + n * 16 + lq, qd);
    if (more) stage_tile<64, 512>(Bgn, E, Bn, tid);
    __builtin_amdgcn_s_barrier();
    asm volatile("s_waitcnt lgkmcnt(0)" ::: "memory");
    __builtin_amdgcn_sched_barrier(0);
    __builtin_amdgcn_s_setprio(1);
#pragma unroll
    for (int jj = 0; jj < 4; ++jj)
#pragma unroll
      for (int n = 0; n < 3; ++n)
        acc[jj][n] = MFMA16(af[jj], bfr[n], acc[jj][n]);
    __builtin_amdgcn_s_setprio(0);
    if (more) asm volatile("s_waitcnt vmcnt(1)" ::: "memory");
    else      asm volatile("s_waitcnt vmcnt(0)" ::: "memory");
    __builtin_amdgcn_s_barrier();

    // ph1: A jj4-7 kk0 (reuse B kk0 frags); stage B1(t+1)
#pragma unroll
    for (int jj = 0; jj < 4; ++jj)
      af[jj] = read_frag(Al, wm * 128 + (4 + jj) * 16 + lq, qd);
    if (more) stage_tile<64, 512>(Bgn + (size_t)64 * E, E, Bn + 64 * 64, tid);
    __builtin_amdgcn_s_barrier();
    asm volatile("s_waitcnt lgkmcnt(0)" ::: "memory");
    __builtin_amdgcn_sched_barrier(0);
    __builtin_amdgcn_s_setprio(1);
#pragma unroll
    for (int jj = 0; jj < 4; ++jj)
#pragma unroll
      for (int n = 0; n < 3; ++n)
        acc[4 + jj][n] = MFMA16(af[jj], bfr[n], acc[4 + jj][n]);
    __builtin_amdgcn_s_setprio(0);
    __builtin_amdgcn_s_barrier();

    // ph2: A jj0-3 kk1 + B kk1; stage B2(t+1) + A0(t+1)
#pragma unroll
    for (int jj = 0; jj < 4; ++jj)
      af[jj] = read_frag(Al, wm * 128 + jj * 16 + lq, 4 + qd);
#pragma unroll
    for (int n = 0; n < 3; ++n)
      bfr[n] = read_frag(Bl, wn * 48 + n * 16 + lq, 4 + qd);
    if (more) {
      stage_tile<64, 512>(Bgn + (size_t)128 * E, E, Bn + 128 * 64, tid);
      stage_A_chunk(Agn, 0, An, tid);
    }
    __builtin_amdgcn_s_barrier();
    asm volatile("s_waitcnt lgkmcnt(0)" ::: "memory");
    __builtin_amdgcn_sched_barrier(0);
    __builtin_amdgcn_s_setprio(1);
#pragma unroll
    for (int jj = 0; jj < 4; ++jj)
#pragma unroll
      for (int n = 0; n < 3; ++n)
        acc[jj][n] = MFMA16(af[jj], bfr[n], acc[jj][n]);
    __builtin_amdgcn_s_setprio(0);
    __builtin_amdgcn_s_barrier();

    // ph3: A jj4-7 kk1; stage A1(t+1)
#pragma unroll
    for (int jj = 0; jj < 4; ++jj)
      af[jj] = read_frag(Al, wm * 128 + (4 + jj) * 16 + lq, 4 + qd);
    if (more) stage_A_chunk(Agn, 1, An, tid);
    __builtin_amdgcn_s_barrier();
    asm volatile("s_waitcnt lgkmcnt(0)" ::: "memory");
    __builtin_amdgcn_sched_barrier(0);
    __builtin_amdgcn_s_setprio(1);
#pragma unroll
    for (int jj = 0; jj < 4; ++jj)
#pragma unroll
      for (int n = 0; n < 3; ++n)
        acc[4 + jj][n] = MFMA16(af[jj], bfr[n], acc[4 + jj][n]);
    __builtin_amdgcn_s_setprio(0);
    if (more) asm volatile("s_waitcnt vmcnt(2)" ::: "memory");
    __builtin_amdgcn_s_barrier();
  }

  // epilogue: per-column routing (192-col tile may span Q/K/V)
#pragma unroll
  for (int n = 0; n < 3; ++n) {
    const int col = n0 + wn * 48 + n * 16 + lq;
    const int mat = col >> 10, cc = col & 1023;
    const float bvv = (mat == 0 ? bq : mat == 1 ? bk : bv)[cc];
    if (mat < 2) {
      const float sc = (mat == 0) ? 0.18033688011112043f : 1.0f;  // log2(e)/8
      bf16_t* Out = QKb + (size_t)mat * ((size_t)M * E);
#pragma unroll
      for (int jj = 0; jj < 8; ++jj)
#pragma unroll
        for (int r = 0; r < 4; ++r) {
          const int row = m0 + wm * 128 + jj * 16 + qd * 4 + r;
          Out[(size_t)row * E + cc] = (bf16_t)((acc[jj][n][r] + bvv) * sc);
        }
    } else {
      // V -> VT sigma-permuted transpose; 4 r-rows -> one bf16x4 store
      const int d = cc & 63, hh = cc >> 6;
#pragma unroll
      for (int jj = 0; jj < 8; ++jj) {
        const int row = m0 + wm * 128 + jj * 16 + qd * 4;  // r=0 base
        const int bb_ = row >> 11;           // batch
        const int s_loc = row & (S - 1);
        const int sl = s_loc & 63, s0 = s_loc & ~63;
        const int a = sl >> 4, b4 = (sl >> 2) & 3;
        const int pb = (a >> 1) * 32 + b4 * 8 + (a & 1) * 4;
        bf16x4 vv;
#pragma unroll
        for (int r = 0; r < 4; ++r) vv[r] = (bf16_t)(acc[jj][n][r] + bvv);
        *(bf16x4*)&VT[((size_t)((bb_ * 16 + hh) * 64 + d)) * S + s0 + pb] = vv;
      }
    }
  }
}

// ---------------------------------------------------------------------------
// output projection: 64x128 tiles -> grid (8, 64) = 512 blocks.
// ---------------------------------------------------------------------------
__global__ __launch_bounds__(256) void oproj_gemm_kernel(
    const bf16_t* __restrict__ Ob, const bf16_t* __restrict__ wo,
    const float* __restrict__ bo, float* __restrict__ out) {
  __shared__ __align__(16) bf16_t As[64 * 64];    // 8 KB
  __shared__ __align__(16) bf16_t Bs[128 * 64];   // 16 KB
  const int tid = threadIdx.x;
  const int n0 = blockIdx.x * 128;
  const int m0 = blockIdx.y * 64;
  const int w = tid >> 6, l = tid & 63, lq = l & 15, qd = l >> 4;
  const int wr = (w >> 1) * 32, wc = (w & 1) * 64;

  f32x4 acc[2][4];
#pragma unroll
  for (int i = 0; i < 2; ++i)
#pragma unroll
    for (int j = 0; j < 4; ++j) acc[i][j] = (f32x4){0.f, 0.f, 0.f, 0.f};

  for (int kt = 0; kt < 16; ++kt) {
    __syncthreads();
    stage_tile<64, 256>(Ob + (size_t)m0 * E + kt * 64, E, As, tid);
    stage_tile<128, 256>(wo + (size_t)n0 * E + kt * 64, E, Bs, tid);
    __syncthreads();
#pragma unroll
    for (int ks = 0; ks < 2; ++ks) {
      bf16x8 af[2], bw[4];
#pragma unroll
      for (int mi = 0; mi < 2; ++mi)
        af[mi] = read_frag(As, wr + mi * 16 + lq, ks * 4 + qd);
#pragma unroll
      for (int ni = 0; ni < 4; ++ni)
        bw[ni] = read_frag(Bs, wc + ni * 16 + lq, ks * 4 + qd);
#pragma unroll
      for (int mi = 0; mi < 2; ++mi)
#pragma unroll
        for (int ni = 0; ni < 4; ++ni)
          acc[mi][ni] = MFMA16(af[mi], bw[ni], acc[mi][ni]);
    }
  }
#pragma unroll
  for (int ni = 0; ni < 4; ++ni) {
    const int col = n0 + wc + ni * 16 + lq;
    const float bvv = bo[col];
#pragma unroll
    for (int mi = 0; mi < 2; ++mi)
#pragma unroll
      for (int r = 0; r < 4; ++r) {
        const int row = m0 + wr + mi * 16 + qd * 4 + r;
        out[(size_t)row * E + col] = acc[mi][ni][r] + bvv;
      }
  }
}

// ---------------------------------------------------------------------------
// causal flash attention v18: KEY-SPLIT STREAMS for 32 q-rows/wave.
// (= v17 with the segment-epilogue PV bug fixed.)
//
// Rationale: K/V LDS fragments depend only on the lane, so FLOP per LDS byte
// = q-rows/wave. v15 (16 rows/wave) had a ~21 us/CU LDS-read floor vs 6.9 us
// MFMA floor. v18 doubles rows/wave to 32 keeping 8 waves/CU:
//  * block = 4 waves: waves {0,1} = stream 0 (even 64-key tiles), waves
//    {2,3} = stream 1 (odd tiles); same 64 q-rows (32 rows/wave). No-max
//    softmax is additive over keys -> independent partial O / rowsum.
//  * Per pair {31-p, p}: both segments run Tm = qt/2+1 shared-barrier
//    iterations (17 total per block, uniform).
//  * Per stream: K dbuf + V tri-buf + PV(kt-1)-overlap + ones-MFMA rowsum.
//    LDS 80 KB -> 2 blocks/CU.
//  * BUGFIX vs v17: segment-epilogue PV runs ONLY if the stream was active
//    in the final shared iteration (2*(Tm-1)+st <= qt). Otherwise its last
//    tile's PV already ran in-loop, and the epilogue would re-apply stale
//    ap_prev against a never-staged V slot (v17's failure: absmax 0.078).
//  * Segment-end merge via global scratch (L2-resident), block-uniform
//    barriers throughout.
// ---------------------------------------------------------------------------
__global__ __launch_bounds__(256, 2) void attn_kernel(
    const bf16_t* __restrict__ Q, const bf16_t* __restrict__ K,
    const bf16_t* __restrict__ VT, bf16_t* __restrict__ O,
    float* __restrict__ scr) {
  __shared__ __align__(16) bf16_t Ks[2][2][64 * 64];  // [stream][slot] 32 KB
  __shared__ __align__(16) bf16_t Vt[2][3][64 * 64];  // [stream][slot] 48 KB

  const int tid = threadIdx.x;
  const int w = tid >> 6, l = tid & 63;
  const int lq = l & 15, qd = l >> 4;
  const int st = w >> 1;        // key stream (0=even tiles, 1=odd)
  const int half = w & 1;       // row half (0: rows 0-31, 1: rows 32-63)
  const int ptid = tid & 127;   // pair-local tid for staging (NT=128)

  const int bid = blockIdx.x;
  const int g = bid & 7, t = bid >> 3;  // 64 blocks per XCD-group
  const int bh = g * 4 + (t & 3);       // 4 bh per XCD-group: L2-resident K/VT
  const int p = t >> 2;                 // pair index: q-tiles {31-p, p}
  const int b = bh >> 4, h = bh & 15;
  const size_t rowbase = (size_t)b * S;
  const bf16_t* Kg = K + rowbase * E + h * 64;
  const bf16_t* Vg = VT + (size_t)bh * 64 * S;
  float* sbase = scr + (size_t)bid * 5120;  // 20 KB per block

  bf16x8 ones;
#pragma unroll
  for (int jj = 0; jj < 8; ++jj) ones[jj] = (bf16_t)1.0f;

#pragma unroll 1
  for (int seg = 0; seg < 2; ++seg) {
    const int qt = seg ? p : 31 - p;       // heavy q-tile first
    const int Tm = (qt >> 1) + 1;          // shared iteration count
    const int qr = qt * 64 + half * 32;    // wave rows [qr, qr+32)
    // stream active in the final shared iteration? (-> epilogue PV owner)
    const bool last_active = (2 * (Tm - 1) + st) <= qt;
    const bool any_tile = (st == 0) || (qt >= 1);

    // Q fragments (pre-scaled): rows qr + mi*16 + lq, MFMA B-operand
    bf16x8 aq[2][2];
#pragma unroll
    for (int mi = 0; mi < 2; ++mi)
#pragma unroll
      for (int ks = 0; ks < 2; ++ks)
        aq[mi][ks] = *(const bf16x8*)(Q + (rowbase + qr + mi * 16 + lq) * E +
                                      h * 64 + ks * 32 + qd * 8);

    f32x4 oacc[2][4];
#pragma unroll
    for (int mi = 0; mi < 2; ++mi)
#pragma unroll
      for (int nt = 0; nt < 4; ++nt) oacc[mi][nt] = (f32x4){0.f, 0.f, 0.f, 0.f};
    f32x4 osum[2] = {(f32x4){0.f, 0.f, 0.f, 0.f}, (f32x4){0.f, 0.f, 0.f, 0.f}};
    bf16x8 ap_prev[2][2];
    int cb = 0, vcur = 0, vprev = 0;

    auto do_pv = [&](const bf16_t* Vp) {
#pragma unroll
      for (int ks = 0; ks < 2; ++ks) {
        bf16x8 bv[4];
#pragma unroll
        for (int nt = 0; nt < 4; ++nt)
          bv[nt] = read_frag(Vp, nt * 16 + lq, ks * 4 + qd);
#pragma unroll
        for (int mi = 0; mi < 2; ++mi)
#pragma unroll
          for (int nt = 0; nt < 4; ++nt)
            oacc[mi][nt] = MFMA16(ap_prev[mi][ks], bv[nt], oacc[mi][nt]);
#pragma unroll
        for (int mi = 0; mi < 2; ++mi)
          osum[mi] = MFMA16(ap_prev[mi][ks], ones, osum[mi]);
      }
    };

    // prologue: stage my stream's tile 0 (global k-tile = st)
    if (any_tile) {
      stage_tile<64, 128>(Kg + (size_t)(st * 64) * E, E, Ks[st][0], ptid);
      stage_tile<64, 128>(Vg + st * 64, S, Vt[st][0], ptid);
    }

    for (int it = 0; it < Tm; ++it) {
      __syncthreads();  // drains each wave's own DMA (tile it landed);
                        // all waves' reads of the slots being rewritten done
      const int vnext = (vcur + 1 == 3) ? 0 : vcur + 1;
      const int ktn = 2 * (it + 1) + st;   // my stream's next tile
      if (ktn <= qt) {
        stage_tile<64, 128>(Kg + (size_t)(ktn * 64) * E, E, Ks[st][cb ^ 1], ptid);
        stage_tile<64, 128>(Vg + ktn * 64, S, Vt[st][vnext], ptid);
      }
      const int kt_g = 2 * it + st;        // my stream's current tile
      const bool active = (kt_g <= qt);

      f32x4 sacc[2][4];
      __builtin_amdgcn_s_setprio(1);
      if (active) {
#pragma unroll
        for (int mi = 0; mi < 2; ++mi)
#pragma unroll
          for (int nt = 0; nt < 4; ++nt) sacc[mi][nt] = (f32x4){0.f, 0.f, 0.f, 0.f};
        const bf16_t* Kc = Ks[st][cb];
#pragma unroll
        for (int ks = 0; ks < 2; ++ks) {
          bf16x8 bk[4];
#pragma unroll
          for (int nt = 0; nt < 4; ++nt)
            bk[nt] = read_frag(Kc, nt * 16 + lq, ks * 4 + qd);
#pragma unroll
          for (int mi = 0; mi < 2; ++mi)
#pragma unroll
            for (int nt = 0; nt < 4; ++nt)
              sacc[mi][nt] = MFMA16(bk[nt], aq[mi][ks], sacc[mi][nt]);
        }
      }
      // PV of my stream's previous tile (overlaps softmax below)
      if (it > 0 && (2 * (it - 1) + st) <= qt) do_pv(Vt[st][vprev]);
      __builtin_amdgcn_s_setprio(0);

      if (active) {
        const int k0 = kt_g * 64;
        if (kt_g == qt) {  // diagonal tile: mask
#pragma unroll
          for (int mi = 0; mi < 2; ++mi) {
            const int qg = qr + mi * 16 + lq;
#pragma unroll
            for (int nt = 0; nt < 4; ++nt)
#pragma unroll
              for (int r = 0; r < 4; ++r) {
                float pv = __builtin_amdgcn_exp2f(sacc[mi][nt][r]);
                const int kg = k0 + nt * 16 + qd * 4 + r;
                pv = (kg > qg) ? 0.f : pv;
                ap_prev[mi][nt >> 1][((nt & 1) << 2) | r] = (bf16_t)pv;
              }
          }
        } else {
#pragma unroll
          for (int mi = 0; mi < 2; ++mi)
#pragma unroll
            for (int nt = 0; nt < 4; ++nt)
#pragma unroll
              for (int r = 0; r < 4; ++r) {
                float pv = __builtin_amdgcn_exp2f(sacc[mi][nt][r]);
                ap_prev[mi][nt >> 1][((nt & 1) << 2) | r] = (bf16_t)pv;
              }
        }
      }
      vprev = vcur;
      vcur = vnext;
      cb ^= 1;
    }
    // epilogue PV: only if my stream processed a tile in the FINAL iteration
    // (otherwise its last PV already ran in-loop; v17 bug was unconditional)
    if (last_active) do_pv(Vt[st][vprev]);

    // ---- cross-stream merge (global scratch, L2-resident) ----
    if (st == 1) {
#pragma unroll
      for (int mi = 0; mi < 2; ++mi)
#pragma unroll
        for (int nt = 0; nt < 4; ++nt)
          *(f32x4*)(sbase + ((size_t)((half * 2 + mi) * 4 + nt)) * 256 + l * 4) =
              oacc[mi][nt];
#pragma unroll
      for (int mi = 0; mi < 2; ++mi)
        *(f32x4*)(sbase + 4096 + (size_t)(half * 2 + mi) * 256 + l * 4) = osum[mi];
      asm volatile("s_waitcnt vmcnt(0)" ::: "memory");
    }
    __syncthreads();
    if (st == 0) {
#pragma unroll
      for (int mi = 0; mi < 2; ++mi)
#pragma unroll
        for (int nt = 0; nt < 4; ++nt)
          oacc[mi][nt] += *(const f32x4*)(sbase +
              ((size_t)((half * 2 + mi) * 4 + nt)) * 256 + l * 4);
#pragma unroll
      for (int mi = 0; mi < 2; ++mi)
        osum[mi] += *(const f32x4*)(sbase + 4096 +
                                    (size_t)(half * 2 + mi) * 256 + l * 4);
#pragma unroll
      for (int mi = 0; mi < 2; ++mi) {
        float rinv[4];
#pragma unroll
        for (int r = 0; r < 4; ++r) rinv[r] = 1.0f / osum[mi][r];
#pragma unroll
        for (int nt = 0; nt < 4; ++nt)
#pragma unroll
          for (int r = 0; r < 4; ++r) {
            const int qgw = qr + mi * 16 + qd * 4 + r;
            O[(rowbase + qgw) * E + h * 64 + nt * 16 + lq] =
                (bf16_t)(oacc[mi][nt][r] * rinv[r]);
          }
      }
    }
  }
}

// ---------------------------------------------------------------------------
// launch
// ---------------------------------------------------------------------------
extern "C" void kernel_launch(void* const* d_in, const int* in_sizes, int n_in,
                              void* d_out, int out_size, void* d_ws, size_t ws_size,
                              hipStream_t stream) {
  const float* x  = (const float*)d_in[0];
  const float* Wq = (const float*)d_in[1];
  const float* bq = (const float*)d_in[2];
  const float* Wk = (const float*)d_in[3];
  const float* bk = (const float*)d_in[4];
  const float* Wv = (const float*)d_in[5];
  const float* bv = (const float*)d_in[6];
  const float* Wo = (const float*)d_in[7];
  const float* bo = (const float*)d_in[8];
  float* out = (float*)d_out;

  unsigned char* ws = (unsigned char*)d_ws;
  constexpr size_t MB = 1ull << 20;
  bf16_t* xb  = (bf16_t*)(ws + 0 * MB);   // 8 MB; reused as Ob after qkv
  bf16_t* wqb = (bf16_t*)(ws + 8 * MB);   // wq/wk/wv contiguous [3072][1024]
  bf16_t* wkb = (bf16_t*)(ws + 10 * MB);
  bf16_t* wvb = (bf16_t*)(ws + 12 * MB);
  bf16_t* wob = (bf16_t*)(ws + 14 * MB);
  bf16_t* Qb  = (bf16_t*)(ws + 16 * MB);  // Q/K contiguous [2][4096][1024]
  bf16_t* VT  = (bf16_t*)(ws + 40 * MB);  // [32 bh][64 d][2048 s, sigma-perm per 64]
  float*  scr = (float*)(ws + 64 * MB);   // 512 blocks x 20 KB merge scratch
  bf16_t* Ob  = xb;                       // xb dead after qkv

  cvt_all_kernel<<<4096 + 4 * 1024, 256, 0, stream>>>(
      x, Wq, Wk, Wv, Wo, xb, wqb, wkb, wvb, wob);

  qkv8_kernel<<<256, 512, 0, stream>>>(xb, wqb, bq, bk, bv, Qb, VT);

  attn_kernel<<<512, 256, 0, stream>>>(Qb, Qb + (size_t)M * E, VT, Ob, scr);

  oproj_gemm_kernel<<<dim3(8, 64), 256, 0, stream>>>(Ob, wob, bo, out);
}

// Round 10
// 170.441 us; speedup vs baseline: 1.0096x; 1.0096x over previous
//
#include <hip/hip_runtime.h>
#include <hip/hip_bf16.h>

typedef __bf16 bf16_t;
typedef __bf16 bf16x8 __attribute__((ext_vector_type(8)));
typedef __bf16 bf16x4 __attribute__((ext_vector_type(4)));
typedef float  f32x4  __attribute__((ext_vector_type(4)));

#define MFMA16(a, b, c) __builtin_amdgcn_mfma_f32_16x16x32_bf16((a), (b), (c), 0, 0, 0)

constexpr int E  = 1024;
constexpr int S  = 2048;
constexpr int H  = 16;
constexpr int M  = 4096;  // B*S

// ---------------------------------------------------------------------------
// async global->LDS 16B (wave-uniform LDS base + lane*16)
// ---------------------------------------------------------------------------
__device__ __forceinline__ void glds16(const bf16_t* src, bf16_t* dst) {
  __builtin_amdgcn_global_load_lds(
      (const __attribute__((address_space(1))) void*)src,
      (__attribute__((address_space(3))) void*)dst, 16, 0, 0);
}

// Stage a [ROWS x 64] bf16 tile (global row stride gld) into LDS, XOR-swizzled.
// NT = participating threads (pass a local tid in [0,NT)).
template <int ROWS, int NT>
__device__ __forceinline__ void stage_tile(const bf16_t* g, int gld,
                                           bf16_t* lds, int tid) {
  const int w = tid >> 6, l = tid & 63;
#pragma unroll
  for (int i = 0; i < ROWS * 8 / NT; ++i) {
    const int c = i * NT + w * 64 + l;
    const int row = c >> 3;
    const int gch = (c & 7) ^ (row & 7);
    glds16(g + (size_t)row * gld + gch * 8, lds + (size_t)(i * NT + w * 64) * 8);
  }
}

// Stage a [64 x 128] bf16 tile (row stride gld) into LDS, XOR-swizzled in
// 16B chunks within each row. NT=256: 4 glds/thread.
__device__ __forceinline__ void stage_v128(const bf16_t* g, int gld,
                                           bf16_t* lds, int tid) {
#pragma unroll
  for (int i = 0; i < 4; ++i) {
    const int c = i * 256 + tid;          // [0,1024)
    const int row = c >> 4, col16 = c & 15;
    const int gch = col16 ^ (row & 7);
    glds16(g + (size_t)row * gld + gch * 8, lds + (size_t)c * 8);
  }
}

// Stage interleaved A-chunk c of a 256-row tile (qkv kernel helper).
__device__ __forceinline__ void stage_A_chunk(const bf16_t* g, int c,
                                              bf16_t* lds, int tid) {
  const int w = tid >> 6, l = tid & 63;
#pragma unroll
  for (int i = 0; i < 2; ++i) {
    const int gc = i * 512 + w * 64 + l;      // [0,1024)
    const int row_l = gc >> 3;                // [0,128)
    const int col8 = gc & 7;
    const int h = row_l >> 6, rr = row_l & 63;
    const int row = h * 128 + c * 64 + rr;    // LDS == global row
    const int gch = col8 ^ (row & 7);
    glds16(g + (size_t)row * E + gch * 8, lds + ((size_t)row * 8 + col8) * 8);
  }
}

// Read an 8-elem k-chunk (kc in [0,8)) of row `row` from a swizzled [R x 64] tile.
__device__ __forceinline__ bf16x8 read_frag(const bf16_t* lds, int row, int kc) {
  return *(const bf16x8*)(lds + (size_t)((row << 3) + (kc ^ (row & 7))) * 8);
}

// Read an 8-elem chunk (kc in [0,16)) of row `row` from a swizzled [64 x 128] tile.
__device__ __forceinline__ bf16x8 read_v128(const bf16_t* lds, int row, int kc) {
  return *(const bf16x8*)(lds + (size_t)((row << 4) + (kc ^ (row & 7))) * 8);
}

// ---------------------------------------------------------------------------
// fused fp32->bf16 conversion, v2: 32B read / 16B write per thread.
// 4096 blocks x 256 thr: blocks [0,2048) -> x (8 f32/thread);
// blocks [2048,4096) -> weights (512 blocks each of wq,wk,wv,wo).
// ---------------------------------------------------------------------------
__global__ void cvt_all_kernel(const float* __restrict__ x,
                               const float* __restrict__ w0, const float* __restrict__ w1,
                               const float* __restrict__ w2, const float* __restrict__ w3,
                               bf16_t* __restrict__ xb,
                               bf16_t* __restrict__ o0, bf16_t* __restrict__ o1,
                               bf16_t* __restrict__ o2, bf16_t* __restrict__ o3) {
  const int bid = blockIdx.x;
  const float* s;
  bf16_t* d;
  int idx;
  if (bid < 2048) {
    s = x; d = xb; idx = bid * 256 + threadIdx.x;
  } else {
    const int seg = (bid - 2048) >> 9;
    s = seg == 0 ? w0 : seg == 1 ? w1 : seg == 2 ? w2 : w3;
    d = seg == 0 ? o0 : seg == 1 ? o1 : seg == 2 ? o2 : o3;
    idx = ((bid - 2048) & 511) * 256 + threadIdx.x;
  }
  float4 v0 = ((const float4*)s)[idx * 2];
  float4 v1 = ((const float4*)s)[idx * 2 + 1];
  bf16x8 o;
  o[0] = (bf16_t)v0.x; o[1] = (bf16_t)v0.y; o[2] = (bf16_t)v0.z; o[3] = (bf16_t)v0.w;
  o[4] = (bf16_t)v1.x; o[5] = (bf16_t)v1.y; o[6] = (bf16_t)v1.z; o[7] = (bf16_t)v1.w;
  ((bf16x8*)d)[idx] = o;
}

// ---------------------------------------------------------------------------
// fused QKV projection, v5 (kept): counted-vmcnt 4-phase schedule at 256x192,
// grid 16x16 = 256 blocks (all CUs). W fused [3072][1024]; Q/K row-major;
// V -> sigma-permuted VT. Q PRE-SCALED by log2(e)/8.
// ---------------------------------------------------------------------------
__global__ __launch_bounds__(512, 1) void qkv8_kernel(
    const bf16_t* __restrict__ xb, const bf16_t* __restrict__ W3,
    const float* __restrict__ bq, const float* __restrict__ bk,
    const float* __restrict__ bv, bf16_t* __restrict__ QKb,
    bf16_t* __restrict__ VT) {
  __shared__ __align__(16) bf16_t As[2][256 * 64];  // 64 KB
  __shared__ __align__(16) bf16_t Bs[2][192 * 64];  // 48 KB
  const int tid = threadIdx.x;
  const int l = tid & 63, lq = l & 15, qd = l >> 4;
  const int w = tid >> 6, wm = w >> 2, wn = w & 3;

  // XCD-aware 4x4-region swizzle over the 16x16 block grid
  const int wg = blockIdx.x;
  const int xcd = wg & 7, i5 = wg >> 3;        // i5 in [0,32)
  const int region = xcd * 2 + (i5 >> 4);      // [0,16)
  const int j = i5 & 15;
  const int bx = (region & 3) * 4 + (j & 3);   // n-tile [0,16)
  const int by = (region >> 2) * 4 + (j >> 2); // m-tile [0,16)
  const int m0 = by * 256, n0 = bx * 192;

  const bf16_t* Ag = xb + (size_t)m0 * E;
  const bf16_t* Bg = W3 + (size_t)n0 * E;

  f32x4 acc[8][3];
#pragma unroll
  for (int jj = 0; jj < 8; ++jj)
#pragma unroll
    for (int n = 0; n < 3; ++n) acc[jj][n] = (f32x4){0.f, 0.f, 0.f, 0.f};

  // prologue: B0,B1,B2,A0,A1 of tile 0 (steady-state issue order)
  stage_tile<64, 512>(Bg, E, Bs[0], tid);
  stage_tile<64, 512>(Bg + (size_t)64 * E, E, Bs[0] + 64 * 64, tid);
  stage_tile<64, 512>(Bg + (size_t)128 * E, E, Bs[0] + 128 * 64, tid);
  stage_A_chunk(Ag, 0, As[0], tid);
  stage_A_chunk(Ag, 1, As[0], tid);
  asm volatile("s_waitcnt vmcnt(2)" ::: "memory");
  __builtin_amdgcn_s_barrier();

#pragma unroll 1
  for (int g = 0; g < 16; ++g) {
    const int s = g & 1;
    const bf16_t* Al = As[s];
    const bf16_t* Bl = Bs[s];
    bf16_t* An = As[s ^ 1];
    bf16_t* Bn = Bs[s ^ 1];
    const bf16_t* Agn = Ag + (g + 1) * 64;
    const bf16_t* Bgn = Bg + (g + 1) * 64;
    const bool more = (g < 15);
    bf16x8 af[4], bfr[3];

    // ph0: A jj0-3 kk0 + B kk0; stage B0(t+1)
#pragma unroll
    for (int jj = 0; jj < 4; ++jj)
      af[jj] = read_frag(Al, wm * 128 + jj * 16 + lq, qd);
#pragma unroll
    for (int n = 0; n < 3; ++n)
      bfr[n] = read_frag(Bl, wn * 48 + n * 16 + lq, qd);
    if (more) stage_tile<64, 512>(Bgn, E, Bn, tid);
    __builtin_amdgcn_s_barrier();
    asm volatile("s_waitcnt lgkmcnt(0)" ::: "memory");
    __builtin_amdgcn_sched_barrier(0);
    __builtin_amdgcn_s_setprio(1);
#pragma unroll
    for (int jj = 0; jj < 4; ++jj)
#pragma unroll
      for (int n = 0; n < 3; ++n)
        acc[jj][n] = MFMA16(af[jj], bfr[n], acc[jj][n]);
    __builtin_amdgcn_s_setprio(0);
    if (more) asm volatile("s_waitcnt vmcnt(1)" ::: "memory");
    else      asm volatile("s_waitcnt vmcnt(0)" ::: "memory");
    __builtin_amdgcn_s_barrier();

    // ph1: A jj4-7 kk0 (reuse B kk0 frags); stage B1(t+1)
#pragma unroll
    for (int jj = 0; jj < 4; ++jj)
      af[jj] = read_frag(Al, wm * 128 + (4 + jj) * 16 + lq, qd);
    if (more) stage_tile<64, 512>(Bgn + (size_t)64 * E, E, Bn + 64 * 64, tid);
    __builtin_amdgcn_s_barrier();
    asm volatile("s_waitcnt lgkmcnt(0)" ::: "memory");
    __builtin_amdgcn_sched_barrier(0);
    __builtin_amdgcn_s_setprio(1);
#pragma unroll
    for (int jj = 0; jj < 4; ++jj)
#pragma unroll
      for (int n = 0; n < 3; ++n)
        acc[4 + jj][n] = MFMA16(af[jj], bfr[n], acc[4 + jj][n]);
    __builtin_amdgcn_s_setprio(0);
    __builtin_amdgcn_s_barrier();

    // ph2: A jj0-3 kk1 + B kk1; stage B2(t+1) + A0(t+1)
#pragma unroll
    for (int jj = 0; jj < 4; ++jj)
      af[jj] = read_frag(Al, wm * 128 + jj * 16 + lq, 4 + qd);
#pragma unroll
    for (int n = 0; n < 3; ++n)
      bfr[n] = read_frag(Bl, wn * 48 + n * 16 + lq, 4 + qd);
    if (more) {
      stage_tile<64, 512>(Bgn + (size_t)128 * E, E, Bn + 128 * 64, tid);
      stage_A_chunk(Agn, 0, An, tid);
    }
    __builtin_amdgcn_s_barrier();
    asm volatile("s_waitcnt lgkmcnt(0)" ::: "memory");
    __builtin_amdgcn_sched_barrier(0);
    __builtin_amdgcn_s_setprio(1);
#pragma unroll
    for (int jj = 0; jj < 4; ++jj)
#pragma unroll
      for (int n = 0; n < 3; ++n)
        acc[jj][n] = MFMA16(af[jj], bfr[n], acc[jj][n]);
    __builtin_amdgcn_s_setprio(0);
    __builtin_amdgcn_s_barrier();

    // ph3: A jj4-7 kk1; stage A1(t+1)
#pragma unroll
    for (int jj = 0; jj < 4; ++jj)
      af[jj] = read_frag(Al, wm * 128 + (4 + jj) * 16 + lq, 4 + qd);
    if (more) stage_A_chunk(Agn, 1, An, tid);
    __builtin_amdgcn_s_barrier();
    asm volatile("s_waitcnt lgkmcnt(0)" ::: "memory");
    __builtin_amdgcn_sched_barrier(0);
    __builtin_amdgcn_s_setprio(1);
#pragma unroll
    for (int jj = 0; jj < 4; ++jj)
#pragma unroll
      for (int n = 0; n < 3; ++n)
        acc[4 + jj][n] = MFMA16(af[jj], bfr[n], acc[4 + jj][n]);
    __builtin_amdgcn_s_setprio(0);
    if (more) asm volatile("s_waitcnt vmcnt(2)" ::: "memory");
    __builtin_amdgcn_s_barrier();
  }

  // epilogue: per-column routing (192-col tile may span Q/K/V)
#pragma unroll
  for (int n = 0; n < 3; ++n) {
    const int col = n0 + wn * 48 + n * 16 + lq;
    const int mat = col >> 10, cc = col & 1023;
    const float bvv = (mat == 0 ? bq : mat == 1 ? bk : bv)[cc];
    if (mat < 2) {
      const float sc = (mat == 0) ? 0.18033688011112043f : 1.0f;  // log2(e)/8
      bf16_t* Out = QKb + (size_t)mat * ((size_t)M * E);
#pragma unroll
      for (int jj = 0; jj < 8; ++jj)
#pragma unroll
        for (int r = 0; r < 4; ++r) {
          const int row = m0 + wm * 128 + jj * 16 + qd * 4 + r;
          Out[(size_t)row * E + cc] = (bf16_t)((acc[jj][n][r] + bvv) * sc);
        }
    } else {
      // V -> VT sigma-permuted transpose; 4 r-rows -> one bf16x4 store
      const int d = cc & 63, hh = cc >> 6;
#pragma unroll
      for (int jj = 0; jj < 8; ++jj) {
        const int row = m0 + wm * 128 + jj * 16 + qd * 4;  // r=0 base
        const int bb_ = row >> 11;           // batch
        const int s_loc = row & (S - 1);
        const int sl = s_loc & 63, s0 = s_loc & ~63;
        const int a = sl >> 4, b4 = (sl >> 2) & 3;
        const int pb = (a >> 1) * 32 + b4 * 8 + (a & 1) * 4;
        bf16x4 vv;
#pragma unroll
        for (int r = 0; r < 4; ++r) vv[r] = (bf16_t)(acc[jj][n][r] + bvv);
        *(bf16x4*)&VT[((size_t)((bb_ * 16 + hh) * 64 + d)) * S + s0 + pb] = vv;
      }
    }
  }
}

// ---------------------------------------------------------------------------
// output projection, v2: 64x128 tiles, TRI-BUFFERED counted-vmcnt pipeline.
// 512 blocks (8 XCD x 8m x 8n swizzle) x 256 thr = 2 blocks/CU, 8 waves/CU.
// LDS 3 x (8+16) KB = 72 KB. Per K-tile: 6 own-loads (A:2, B:4).
// Schedule per kt: { s_barrier (all waves done reading slot kt-1 = stage
// target); stage tile kt+2 into that slot; compute tile kt; vmcnt(6) ->
// tile kt+1's own loads landed (kt+2's 6 may fly) }. Gate-then-barrier:
// next iter's barrier makes kt+1 landed block-wide. Never vmcnt(0) mid-loop
// (tail: vmcnt(0) at kt=14 only). Raw s_barrier (no implicit drain).
// ---------------------------------------------------------------------------
__global__ __launch_bounds__(256, 2) void oproj_gemm_kernel(
    const bf16_t* __restrict__ Ob, const bf16_t* __restrict__ wo,
    const float* __restrict__ bo, float* __restrict__ out) {
  __shared__ __align__(16) bf16_t As[3][64 * 64];    // 24 KB
  __shared__ __align__(16) bf16_t Bs[3][128 * 64];   // 48 KB
  const int tid = threadIdx.x;
  const int w = tid >> 6, l = tid & 63, lq = l & 15, qd = l >> 4;
  const int wr = (w >> 1) * 32, wc = (w & 1) * 64;

  // XCD swizzle: 512 blocks = 8 XCD x (8 m-rows x 8 n-cols)
  const int swz = (blockIdx.x & 7) * 64 + (blockIdx.x >> 3);
  const int m0 = (swz >> 3) * 64, n0 = (swz & 7) * 128;
  const bf16_t* Ag = Ob + (size_t)m0 * E;
  const bf16_t* Bg = wo + (size_t)n0 * E;

  f32x4 acc[2][4];
#pragma unroll
  for (int i = 0; i < 2; ++i)
#pragma unroll
    for (int jj = 0; jj < 4; ++jj) acc[i][jj] = (f32x4){0.f, 0.f, 0.f, 0.f};

  // prologue: stage tiles 0 and 1
  stage_tile<64, 256>(Ag, E, As[0], tid);
  stage_tile<128, 256>(Bg, E, Bs[0], tid);
  stage_tile<64, 256>(Ag + 64, E, As[1], tid);
  stage_tile<128, 256>(Bg + 64, E, Bs[1], tid);
  asm volatile("s_waitcnt vmcnt(6)" ::: "memory");  // tile 0 landed (own)

  int rd = 0, stg = 2;  // read slot = kt%3; stage slot = (kt+2)%3
#pragma unroll 1
  for (int kt = 0; kt < 16; ++kt) {
    __builtin_amdgcn_s_barrier();  // all waves: tile kt landed (gate last
                                   // iter) AND done reading slot stg
    if (kt < 14) {
      stage_tile<64, 256>(Ag + (kt + 2) * 64, E, As[stg], tid);
      stage_tile<128, 256>(Bg + (kt + 2) * 64, E, Bs[stg], tid);
    }
    const bf16_t* Al = As[rd];
    const bf16_t* Bl = Bs[rd];
#pragma unroll
    for (int ks = 0; ks < 2; ++ks) {
      bf16x8 af[2], bw[4];
#pragma unroll
      for (int mi = 0; mi < 2; ++mi)
        af[mi] = read_frag(Al, wr + mi * 16 + lq, ks * 4 + qd);
#pragma unroll
      for (int ni = 0; ni < 4; ++ni)
        bw[ni] = read_frag(Bl, wc + ni * 16 + lq, ks * 4 + qd);
#pragma unroll
      for (int mi = 0; mi < 2; ++mi)
#pragma unroll
        for (int ni = 0; ni < 4; ++ni)
          acc[mi][ni] = MFMA16(af[mi], bw[ni], acc[mi][ni]);
    }
    if (kt < 14)       asm volatile("s_waitcnt vmcnt(6)" ::: "memory");
    else if (kt == 14) asm volatile("s_waitcnt vmcnt(0)" ::: "memory");
    stg = rd;
    rd = (rd + 1 == 3) ? 0 : rd + 1;
  }

#pragma unroll
  for (int ni = 0; ni < 4; ++ni) {
    const int col = n0 + wc + ni * 16 + lq;
    const float bvv = bo[col];
#pragma unroll
    for (int mi = 0; mi < 2; ++mi)
#pragma unroll
      for (int r = 0; r < 4; ++r) {
        const int row = m0 + wr + mi * 16 + qd * 4 + r;
        out[(size_t)row * E + col] = acc[mi][ni][r] + bvv;
      }
  }
}

// ---------------------------------------------------------------------------
// causal flash attention v15 (reverted from v18: key-split streams were
// NEUTRAL, so keep the simpler structure): operand-swapped S^T = K*Q^T;
// keys sigma-permuted in VT; P never touches LDS.
//  * KVBLK=128 (two 64-key tiles per barrier); T(qt)=ceil((qt+1)/2);
//    TA+TB = 17 tiles for every pair {31-p, p}; mask only on last tile.
//  * PV(kt-1) issued between QK(kt) and softmax(kt): softmax VALU overlaps
//    PV on the MFMA pipe. V TRIPLE-buffered; K dbuf. LDS 80 KB = 2 blocks/CU.
//  * ROW-SUM VIA ones-MFMA: osum[r] = rowsum for row qd*4+r = O-write layout.
// Uniform work, 512 blocks x 256 thr, 8 waves/CU flat. No-max softmax
// (Q pre-scaled by log2e/8). XCD map g=bid&7 -> bh [4g,4g+4).
// ---------------------------------------------------------------------------
__global__ __launch_bounds__(256, 2) void attn_kernel(
    const bf16_t* __restrict__ Q, const bf16_t* __restrict__ K,
    const bf16_t* __restrict__ VT, bf16_t* __restrict__ O) {
  __shared__ __align__(16) bf16_t Ks[2][128 * 64];  // K dbuf, 32 KB
  __shared__ __align__(16) bf16_t Vt[3][64 * 128];  // V tri-buf, 48 KB

  const int tid = threadIdx.x;
  const int w = tid >> 6, l = tid & 63;
  const int lq = l & 15, qd = l >> 4;
  const int bid = blockIdx.x;
  const int g = bid & 7, t = bid >> 3;  // 64 blocks per XCD-group
  const int bh = g * 4 + (t & 3);       // 4 bh per XCD-group: L2-resident K/VT
  const int p = t >> 2;                 // pair index: q-tiles {31-p, p}
  const int b = bh >> 4, h = bh & 15;
  const size_t rowbase = (size_t)b * S;
  const bf16_t* Kg = K + rowbase * E + h * 64;
  const bf16_t* Vg = VT + (size_t)bh * 64 * S;

  bf16x8 ones;
#pragma unroll
  for (int jj = 0; jj < 8; ++jj) ones[jj] = (bf16_t)1.0f;

  // prefetch 128-key tile 0 into K slot 0 / V slot 0
  stage_tile<128, 256>(Kg, E, Ks[0], tid);
  stage_v128(Vg, S, Vt[0], tid);
  int cb = 0, vcur = 0;

#pragma unroll 1
  for (int seg = 0; seg < 2; ++seg) {
    const int qt = seg ? p : 31 - p;    // heavy q-tile first
    const int T = (qt + 2) >> 1;        // 128-key tiles this segment
    const int qr = qt * 64 + w * 16;    // wave rows [qr, qr+16)
    const int qg = qr + lq;             // this lane's query row

    bf16x8 aq[2];
#pragma unroll
    for (int ks = 0; ks < 2; ++ks)
      aq[ks] = *(const bf16x8*)(Q + (rowbase + qr + lq) * E + h * 64 +
                                ks * 32 + qd * 8);

    f32x4 oacc[4];
#pragma unroll
    for (int nt = 0; nt < 4; ++nt) oacc[nt] = (f32x4){0.f, 0.f, 0.f, 0.f};
    f32x4 osum = (f32x4){0.f, 0.f, 0.f, 0.f};
    bf16x8 ap_prev[4];                   // P frags of tile kt-1 (128 keys)
    int vprev = vcur;

    // PV of the previous tile: 16 oacc-MFMA + 4 ones-MFMA
    auto do_pv = [&](const bf16_t* Vp) {
#pragma unroll
      for (int c = 0; c < 4; ++c) {
        bf16x8 bv[4];
#pragma unroll
        for (int nt = 0; nt < 4; ++nt)
          bv[nt] = read_v128(Vp, nt * 16 + lq, c * 4 + qd);
#pragma unroll
        for (int nt = 0; nt < 4; ++nt)
          oacc[nt] = MFMA16(ap_prev[c], bv[nt], oacc[nt]);
        osum = MFMA16(ap_prev[c], ones, osum);
      }
    };

    for (int kt = 0; kt < T; ++kt) {
      __syncthreads();  // drains DMA into K[cb]/V[vcur]; all waves' reads of
                        // the slots being rewritten completed last iteration
      const int vnext = (vcur + 1 == 3) ? 0 : vcur + 1;
      if (kt < T - 1) {
        const int kn = (kt + 1) * 128;
        stage_tile<128, 256>(Kg + (size_t)kn * E, E, Ks[cb ^ 1], tid);
        stage_v128(Vg + kn, S, Vt[vnext], tid);
      } else if (seg == 0) {      // last A-iter: prefetch segment B's tile 0
        stage_tile<128, 256>(Kg, E, Ks[cb ^ 1], tid);
        stage_v128(Vg, S, Vt[vnext], tid);
      }
      const bf16_t* Kc = Ks[cb];
      const int k0 = kt * 128;
      const bool needmask = (kt == T - 1);

      // ---- S^T = K * Q^T : 16 MFMA; lane holds q=lq, keys nt*16+qd*4+r ----
      f32x4 sacc[8];
#pragma unroll
      for (int nt = 0; nt < 8; ++nt) sacc[nt] = (f32x4){0.f, 0.f, 0.f, 0.f};
      __builtin_amdgcn_s_setprio(1);
#pragma unroll
      for (int ks = 0; ks < 2; ++ks) {
        bf16x8 bk[8];
#pragma unroll
        for (int nt = 0; nt < 8; ++nt)
          bk[nt] = read_frag(Kc, nt * 16 + lq, ks * 4 + qd);
#pragma unroll
        for (int nt = 0; nt < 8; ++nt)
          sacc[nt] = MFMA16(bk[nt], aq[ks], sacc[nt]);
      }
      // ---- PV of tile kt-1 (independent; overlaps softmax below) ----
      if (kt > 0) do_pv(Vt[vprev]);
      __builtin_amdgcn_s_setprio(0);

      // ---- softmax in registers; pack into PV A-frags (VT sigma layout) ----
      if (needmask) {
#pragma unroll
        for (int nt = 0; nt < 8; ++nt)
#pragma unroll
          for (int r = 0; r < 4; ++r) {
            float pv = __builtin_amdgcn_exp2f(sacc[nt][r]);
            const int kg = k0 + nt * 16 + qd * 4 + r;
            pv = (kg > qg) ? 0.f : pv;
            ap_prev[nt >> 1][((nt & 1) << 2) | r] = (bf16_t)pv;
          }
      } else {
#pragma unroll
        for (int nt = 0; nt < 8; ++nt)
#pragma unroll
          for (int r = 0; r < 4; ++r) {
            float pv = __builtin_amdgcn_exp2f(sacc[nt][r]);
            ap_prev[nt >> 1][((nt & 1) << 2) | r] = (bf16_t)pv;
          }
      }
      vprev = vcur;
      vcur = vnext;
      cb ^= 1;
    }
    // epilogue: PV of the segment's last tile
    do_pv(Vt[vprev]);

    // normalize + store: osum[r] = rowsum for q-row qd*4+r = C-layout rows
    float rinv[4];
#pragma unroll
    for (int r = 0; r < 4; ++r) rinv[r] = 1.0f / osum[r];
#pragma unroll
    for (int nt = 0; nt < 4; ++nt)
#pragma unroll
      for (int r = 0; r < 4; ++r) {
        const int qgw = qr + qd * 4 + r;
        O[(rowbase + qgw) * E + h * 64 + nt * 16 + lq] =
            (bf16_t)(oacc[nt][r] * rinv[r]);
      }
  }
}

// ---------------------------------------------------------------------------
// launch
// ---------------------------------------------------------------------------
extern "C" void kernel_launch(void* const* d_in, const int* in_sizes, int n_in,
                              void* d_out, int out_size, void* d_ws, size_t ws_size,
                              hipStream_t stream) {
  const float* x  = (const float*)d_in[0];
  const float* Wq = (const float*)d_in[1];
  const float* bq = (const float*)d_in[2];
  const float* Wk = (const float*)d_in[3];
  const float* bk = (const float*)d_in[4];
  const float* Wv = (const float*)d_in[5];
  const float* bv = (const float*)d_in[6];
  const float* Wo = (const float*)d_in[7];
  const float* bo = (const float*)d_in[8];
  float* out = (float*)d_out;

  unsigned char* ws = (unsigned char*)d_ws;
  constexpr size_t MB = 1ull << 20;
  bf16_t* xb  = (bf16_t*)(ws + 0 * MB);   // 8 MB; reused as Ob after qkv
  bf16_t* wqb = (bf16_t*)(ws + 8 * MB);   // wq/wk/wv contiguous [3072][1024]
  bf16_t* wkb = (bf16_t*)(ws + 10 * MB);
  bf16_t* wvb = (bf16_t*)(ws + 12 * MB);
  bf16_t* wob = (bf16_t*)(ws + 14 * MB);
  bf16_t* Qb  = (bf16_t*)(ws + 16 * MB);  // Q/K contiguous [2][4096][1024]
  bf16_t* VT  = (bf16_t*)(ws + 40 * MB);  // [32 bh][64 d][2048 s, sigma-perm per 64]
  bf16_t* Ob  = xb;                       // xb dead after qkv

  cvt_all_kernel<<<4096, 256, 0, stream>>>(
      x, Wq, Wk, Wv, Wo, xb, wqb, wkb, wvb, wob);

  qkv8_kernel<<<256, 512, 0, stream>>>(xb, wqb, bq, bk, bv, Qb, VT);

  attn_kernel<<<512, 256, 0, stream>>>(Qb, Qb + (size_t)M * E, VT, Ob);

  oproj_gemm_kernel<<<512, 256, 0, stream>>>(Ob, wob, bo, out);
}

// Round 11
// 168.163 us; speedup vs baseline: 1.0232x; 1.0135x over previous
//
#include <hip/hip_runtime.h>
#include <hip/hip_bf16.h>

typedef __bf16 bf16_t;
typedef __bf16 bf16x8 __attribute__((ext_vector_type(8)));
typedef __bf16 bf16x4 __attribute__((ext_vector_type(4)));
typedef float  f32x4  __attribute__((ext_vector_type(4)));

#define MFMA16(a, b, c) __builtin_amdgcn_mfma_f32_16x16x32_bf16((a), (b), (c), 0, 0, 0)

constexpr int E  = 1024;
constexpr int S  = 2048;
constexpr int H  = 16;
constexpr int M  = 4096;  // B*S

// ---------------------------------------------------------------------------
// async global->LDS 16B (wave-uniform LDS base + lane*16)
// ---------------------------------------------------------------------------
__device__ __forceinline__ void glds16(const bf16_t* src, bf16_t* dst) {
  __builtin_amdgcn_global_load_lds(
      (const __attribute__((address_space(1))) void*)src,
      (__attribute__((address_space(3))) void*)dst, 16, 0, 0);
}

// Stage a [ROWS x 64] bf16 tile (global row stride gld) into LDS, XOR-swizzled.
// NT = participating threads (pass a local tid in [0,NT)).
template <int ROWS, int NT>
__device__ __forceinline__ void stage_tile(const bf16_t* g, int gld,
                                           bf16_t* lds, int tid) {
  const int w = tid >> 6, l = tid & 63;
#pragma unroll
  for (int i = 0; i < ROWS * 8 / NT; ++i) {
    const int c = i * NT + w * 64 + l;
    const int row = c >> 3;
    const int gch = (c & 7) ^ (row & 7);
    glds16(g + (size_t)row * gld + gch * 8, lds + (size_t)(i * NT + w * 64) * 8);
  }
}

// Stage a [64 x 128] bf16 tile (row stride gld) into LDS, XOR-swizzled in
// 16B chunks within each row. NT=256: 4 glds/thread.
__device__ __forceinline__ void stage_v128(const bf16_t* g, int gld,
                                           bf16_t* lds, int tid) {
#pragma unroll
  for (int i = 0; i < 4; ++i) {
    const int c = i * 256 + tid;          // [0,1024)
    const int row = c >> 4, col16 = c & 15;
    const int gch = col16 ^ (row & 7);
    glds16(g + (size_t)row * gld + gch * 8, lds + (size_t)c * 8);
  }
}

// Stage interleaved A-chunk c of a 256-row tile (qkv kernel helper).
__device__ __forceinline__ void stage_A_chunk(const bf16_t* g, int c,
                                              bf16_t* lds, int tid) {
  const int w = tid >> 6, l = tid & 63;
#pragma unroll
  for (int i = 0; i < 2; ++i) {
    const int gc = i * 512 + w * 64 + l;      // [0,1024)
    const int row_l = gc >> 3;                // [0,128)
    const int col8 = gc & 7;
    const int h = row_l >> 6, rr = row_l & 63;
    const int row = h * 128 + c * 64 + rr;    // LDS == global row
    const int gch = col8 ^ (row & 7);
    glds16(g + (size_t)row * E + gch * 8, lds + ((size_t)row * 8 + col8) * 8);
  }
}

// Read an 8-elem k-chunk (kc in [0,8)) of row `row` from a swizzled [R x 64] tile.
__device__ __forceinline__ bf16x8 read_frag(const bf16_t* lds, int row, int kc) {
  return *(const bf16x8*)(lds + (size_t)((row << 3) + (kc ^ (row & 7))) * 8);
}

// Read an 8-elem chunk (kc in [0,16)) of row `row` from a swizzled [64 x 128] tile.
__device__ __forceinline__ bf16x8 read_v128(const bf16_t* lds, int row, int kc) {
  return *(const bf16x8*)(lds + (size_t)((row << 4) + (kc ^ (row & 7))) * 8);
}

// pack 2 f32 -> 1 u32 of 2 bf16 (lo=a, hi=b), one full-rate inst (T12)
__device__ __forceinline__ unsigned cvtpk(float a, float b) {
  unsigned r;
  asm("v_cvt_pk_bf16_f32 %0, %1, %2" : "=v"(r) : "v"(a), "v"(b));
  return r;
}

// ---------------------------------------------------------------------------
// fused fp32->bf16 conversion, v2: 32B read / 16B write per thread.
// ---------------------------------------------------------------------------
__global__ void cvt_all_kernel(const float* __restrict__ x,
                               const float* __restrict__ w0, const float* __restrict__ w1,
                               const float* __restrict__ w2, const float* __restrict__ w3,
                               bf16_t* __restrict__ xb,
                               bf16_t* __restrict__ o0, bf16_t* __restrict__ o1,
                               bf16_t* __restrict__ o2, bf16_t* __restrict__ o3) {
  const int bid = blockIdx.x;
  const float* s;
  bf16_t* d;
  int idx;
  if (bid < 2048) {
    s = x; d = xb; idx = bid * 256 + threadIdx.x;
  } else {
    const int seg = (bid - 2048) >> 9;
    s = seg == 0 ? w0 : seg == 1 ? w1 : seg == 2 ? w2 : w3;
    d = seg == 0 ? o0 : seg == 1 ? o1 : seg == 2 ? o2 : o3;
    idx = ((bid - 2048) & 511) * 256 + threadIdx.x;
  }
  float4 v0 = ((const float4*)s)[idx * 2];
  float4 v1 = ((const float4*)s)[idx * 2 + 1];
  bf16x8 o;
  o[0] = (bf16_t)v0.x; o[1] = (bf16_t)v0.y; o[2] = (bf16_t)v0.z; o[3] = (bf16_t)v0.w;
  o[4] = (bf16_t)v1.x; o[5] = (bf16_t)v1.y; o[6] = (bf16_t)v1.z; o[7] = (bf16_t)v1.w;
  ((bf16x8*)d)[idx] = o;
}

// ---------------------------------------------------------------------------
// fused QKV projection, v5 (kept): counted-vmcnt 4-phase schedule at 256x192,
// grid 16x16 = 256 blocks (all CUs). W fused [3072][1024]; Q/K row-major;
// V -> sigma-permuted VT. Q PRE-SCALED by log2(e)/8.
// ---------------------------------------------------------------------------
__global__ __launch_bounds__(512, 1) void qkv8_kernel(
    const bf16_t* __restrict__ xb, const bf16_t* __restrict__ W3,
    const float* __restrict__ bq, const float* __restrict__ bk,
    const float* __restrict__ bv, bf16_t* __restrict__ QKb,
    bf16_t* __restrict__ VT) {
  __shared__ __align__(16) bf16_t As[2][256 * 64];  // 64 KB
  __shared__ __align__(16) bf16_t Bs[2][192 * 64];  // 48 KB
  const int tid = threadIdx.x;
  const int l = tid & 63, lq = l & 15, qd = l >> 4;
  const int w = tid >> 6, wm = w >> 2, wn = w & 3;

  // XCD-aware 4x4-region swizzle over the 16x16 block grid
  const int wg = blockIdx.x;
  const int xcd = wg & 7, i5 = wg >> 3;        // i5 in [0,32)
  const int region = xcd * 2 + (i5 >> 4);      // [0,16)
  const int j = i5 & 15;
  const int bx = (region & 3) * 4 + (j & 3);   // n-tile [0,16)
  const int by = (region >> 2) * 4 + (j >> 2); // m-tile [0,16)
  const int m0 = by * 256, n0 = bx * 192;

  const bf16_t* Ag = xb + (size_t)m0 * E;
  const bf16_t* Bg = W3 + (size_t)n0 * E;

  f32x4 acc[8][3];
#pragma unroll
  for (int jj = 0; jj < 8; ++jj)
#pragma unroll
    for (int n = 0; n < 3; ++n) acc[jj][n] = (f32x4){0.f, 0.f, 0.f, 0.f};

  // prologue: B0,B1,B2,A0,A1 of tile 0 (steady-state issue order)
  stage_tile<64, 512>(Bg, E, Bs[0], tid);
  stage_tile<64, 512>(Bg + (size_t)64 * E, E, Bs[0] + 64 * 64, tid);
  stage_tile<64, 512>(Bg + (size_t)128 * E, E, Bs[0] + 128 * 64, tid);
  stage_A_chunk(Ag, 0, As[0], tid);
  stage_A_chunk(Ag, 1, As[0], tid);
  asm volatile("s_waitcnt vmcnt(2)" ::: "memory");
  __builtin_amdgcn_s_barrier();

#pragma unroll 1
  for (int g = 0; g < 16; ++g) {
    const int s = g & 1;
    const bf16_t* Al = As[s];
    const bf16_t* Bl = Bs[s];
    bf16_t* An = As[s ^ 1];
    bf16_t* Bn = Bs[s ^ 1];
    const bf16_t* Agn = Ag + (g + 1) * 64;
    const bf16_t* Bgn = Bg + (g + 1) * 64;
    const bool more = (g < 15);
    bf16x8 af[4], bfr[3];

    // ph0: A jj0-3 kk0 + B kk0; stage B0(t+1)
#pragma unroll
    for (int jj = 0; jj < 4; ++jj)
      af[jj] = read_frag(Al, wm * 128 + jj * 16 + lq, qd);
#pragma unroll
    for (int n = 0; n < 3; ++n)
      bfr[n] = read_frag(Bl, wn * 48 + n * 16 + lq, qd);
    if (more) stage_tile<64, 512>(Bgn, E, Bn, tid);
    __builtin_amdgcn_s_barrier();
    asm volatile("s_waitcnt lgkmcnt(0)" ::: "memory");
    __builtin_amdgcn_sched_barrier(0);
    __builtin_amdgcn_s_setprio(1);
#pragma unroll
    for (int jj = 0; jj < 4; ++jj)
#pragma unroll
      for (int n = 0; n < 3; ++n)
        acc[jj][n] = MFMA16(af[jj], bfr[n], acc[jj][n]);
    __builtin_amdgcn_s_setprio(0);
    if (more) asm volatile("s_waitcnt vmcnt(1)" ::: "memory");
    else      asm volatile("s_waitcnt vmcnt(0)" ::: "memory");
    __builtin_amdgcn_s_barrier();

    // ph1: A jj4-7 kk0 (reuse B kk0 frags); stage B1(t+1)
#pragma unroll
    for (int jj = 0; jj < 4; ++jj)
      af[jj] = read_frag(Al, wm * 128 + (4 + jj) * 16 + lq, qd);
    if (more) stage_tile<64, 512>(Bgn + (size_t)64 * E, E, Bn + 64 * 64, tid);
    __builtin_amdgcn_s_barrier();
    asm volatile("s_waitcnt lgkmcnt(0)" ::: "memory");
    __builtin_amdgcn_sched_barrier(0);
    __builtin_amdgcn_s_setprio(1);
#pragma unroll
    for (int jj = 0; jj < 4; ++jj)
#pragma unroll
      for (int n = 0; n < 3; ++n)
        acc[4 + jj][n] = MFMA16(af[jj], bfr[n], acc[4 + jj][n]);
    __builtin_amdgcn_s_setprio(0);
    __builtin_amdgcn_s_barrier();

    // ph2: A jj0-3 kk1 + B kk1; stage B2(t+1) + A0(t+1)
#pragma unroll
    for (int jj = 0; jj < 4; ++jj)
      af[jj] = read_frag(Al, wm * 128 + jj * 16 + lq, 4 + qd);
#pragma unroll
    for (int n = 0; n < 3; ++n)
      bfr[n] = read_frag(Bl, wn * 48 + n * 16 + lq, 4 + qd);
    if (more) {
      stage_tile<64, 512>(Bgn + (size_t)128 * E, E, Bn + 128 * 64, tid);
      stage_A_chunk(Agn, 0, An, tid);
    }
    __builtin_amdgcn_s_barrier();
    asm volatile("s_waitcnt lgkmcnt(0)" ::: "memory");
    __builtin_amdgcn_sched_barrier(0);
    __builtin_amdgcn_s_setprio(1);
#pragma unroll
    for (int jj = 0; jj < 4; ++jj)
#pragma unroll
      for (int n = 0; n < 3; ++n)
        acc[jj][n] = MFMA16(af[jj], bfr[n], acc[jj][n]);
    __builtin_amdgcn_s_setprio(0);
    __builtin_amdgcn_s_barrier();

    // ph3: A jj4-7 kk1; stage A1(t+1)
#pragma unroll
    for (int jj = 0; jj < 4; ++jj)
      af[jj] = read_frag(Al, wm * 128 + (4 + jj) * 16 + lq, 4 + qd);
    if (more) stage_A_chunk(Agn, 1, An, tid);
    __builtin_amdgcn_s_barrier();
    asm volatile("s_waitcnt lgkmcnt(0)" ::: "memory");
    __builtin_amdgcn_sched_barrier(0);
    __builtin_amdgcn_s_setprio(1);
#pragma unroll
    for (int jj = 0; jj < 4; ++jj)
#pragma unroll
      for (int n = 0; n < 3; ++n)
        acc[4 + jj][n] = MFMA16(af[jj], bfr[n], acc[4 + jj][n]);
    __builtin_amdgcn_s_setprio(0);
    if (more) asm volatile("s_waitcnt vmcnt(2)" ::: "memory");
    __builtin_amdgcn_s_barrier();
  }

  // epilogue: per-column routing (192-col tile may span Q/K/V)
#pragma unroll
  for (int n = 0; n < 3; ++n) {
    const int col = n0 + wn * 48 + n * 16 + lq;
    const int mat = col >> 10, cc = col & 1023;
    const float bvv = (mat == 0 ? bq : mat == 1 ? bk : bv)[cc];
    if (mat < 2) {
      const float sc = (mat == 0) ? 0.18033688011112043f : 1.0f;  // log2(e)/8
      bf16_t* Out = QKb + (size_t)mat * ((size_t)M * E);
#pragma unroll
      for (int jj = 0; jj < 8; ++jj)
#pragma unroll
        for (int r = 0; r < 4; ++r) {
          const int row = m0 + wm * 128 + jj * 16 + qd * 4 + r;
          Out[(size_t)row * E + cc] = (bf16_t)((acc[jj][n][r] + bvv) * sc);
        }
    } else {
      // V -> VT sigma-permuted transpose; 4 r-rows -> one bf16x4 store
      const int d = cc & 63, hh = cc >> 6;
#pragma unroll
      for (int jj = 0; jj < 8; ++jj) {
        const int row = m0 + wm * 128 + jj * 16 + qd * 4;  // r=0 base
        const int bb_ = row >> 11;           // batch
        const int s_loc = row & (S - 1);
        const int sl = s_loc & 63, s0 = s_loc & ~63;
        const int a = sl >> 4, b4 = (sl >> 2) & 3;
        const int pb = (a >> 1) * 32 + b4 * 8 + (a & 1) * 4;
        bf16x4 vv;
#pragma unroll
        for (int r = 0; r < 4; ++r) vv[r] = (bf16_t)(acc[jj][n][r] + bvv);
        *(bf16x4*)&VT[((size_t)((bb_ * 16 + hh) * 64 + d)) * S + s0 + pb] = vv;
      }
    }
  }
}

// ---------------------------------------------------------------------------
// output projection, v2 (kept): 64x128 tiles, tri-buffered counted-vmcnt.
// ---------------------------------------------------------------------------
__global__ __launch_bounds__(256, 2) void oproj_gemm_kernel(
    const bf16_t* __restrict__ Ob, const bf16_t* __restrict__ wo,
    const float* __restrict__ bo, float* __restrict__ out) {
  __shared__ __align__(16) bf16_t As[3][64 * 64];    // 24 KB
  __shared__ __align__(16) bf16_t Bs[3][128 * 64];   // 48 KB
  const int tid = threadIdx.x;
  const int w = tid >> 6, l = tid & 63, lq = l & 15, qd = l >> 4;
  const int wr = (w >> 1) * 32, wc = (w & 1) * 64;

  // XCD swizzle: 512 blocks = 8 XCD x (8 m-rows x 8 n-cols)
  const int swz = (blockIdx.x & 7) * 64 + (blockIdx.x >> 3);
  const int m0 = (swz >> 3) * 64, n0 = (swz & 7) * 128;
  const bf16_t* Ag = Ob + (size_t)m0 * E;
  const bf16_t* Bg = wo + (size_t)n0 * E;

  f32x4 acc[2][4];
#pragma unroll
  for (int i = 0; i < 2; ++i)
#pragma unroll
    for (int jj = 0; jj < 4; ++jj) acc[i][jj] = (f32x4){0.f, 0.f, 0.f, 0.f};

  // prologue: stage tiles 0 and 1
  stage_tile<64, 256>(Ag, E, As[0], tid);
  stage_tile<128, 256>(Bg, E, Bs[0], tid);
  stage_tile<64, 256>(Ag + 64, E, As[1], tid);
  stage_tile<128, 256>(Bg + 64, E, Bs[1], tid);
  asm volatile("s_waitcnt vmcnt(6)" ::: "memory");  // tile 0 landed (own)

  int rd = 0, stg = 2;  // read slot = kt%3; stage slot = (kt+2)%3
#pragma unroll 1
  for (int kt = 0; kt < 16; ++kt) {
    __builtin_amdgcn_s_barrier();  // all waves: tile kt landed (gate last
                                   // iter) AND done reading slot stg
    if (kt < 14) {
      stage_tile<64, 256>(Ag + (kt + 2) * 64, E, As[stg], tid);
      stage_tile<128, 256>(Bg + (kt + 2) * 64, E, Bs[stg], tid);
    }
    const bf16_t* Al = As[rd];
    const bf16_t* Bl = Bs[rd];
#pragma unroll
    for (int ks = 0; ks < 2; ++ks) {
      bf16x8 af[2], bw[4];
#pragma unroll
      for (int mi = 0; mi < 2; ++mi)
        af[mi] = read_frag(Al, wr + mi * 16 + lq, ks * 4 + qd);
#pragma unroll
      for (int ni = 0; ni < 4; ++ni)
        bw[ni] = read_frag(Bl, wc + ni * 16 + lq, ks * 4 + qd);
#pragma unroll
      for (int mi = 0; mi < 2; ++mi)
#pragma unroll
        for (int ni = 0; ni < 4; ++ni)
          acc[mi][ni] = MFMA16(af[mi], bw[ni], acc[mi][ni]);
    }
    if (kt < 14)       asm volatile("s_waitcnt vmcnt(6)" ::: "memory");
    else if (kt == 14) asm volatile("s_waitcnt vmcnt(0)" ::: "memory");
    stg = rd;
    rd = (rd + 1 == 3) ? 0 : rd + 1;
  }

#pragma unroll
  for (int ni = 0; ni < 4; ++ni) {
    const int col = n0 + wc + ni * 16 + lq;
    const float bvv = bo[col];
#pragma unroll
    for (int mi = 0; mi < 2; ++mi)
#pragma unroll
      for (int r = 0; r < 4; ++r) {
        const int row = m0 + wr + mi * 16 + qd * 4 + r;
        out[(size_t)row * E + col] = acc[mi][ni][r] + bvv;
      }
  }
}

// ---------------------------------------------------------------------------
// causal flash attention v16 = v15 + cvt_pk P-packing (T12 primitive).
// Operand-swapped S^T = K*Q^T; keys sigma-permuted in VT; P never in LDS.
//  * KVBLK=128; T(qt)=ceil((qt+1)/2); 17 tiles per pair {31-p, p}.
//  * PV(kt-1) overlaps softmax(kt); V tri-buf, K dbuf; LDS 80 KB.
//  * rowsum via ones-MFMA (layout = O-write layout).
//  * NEW: P packed with v_cvt_pk_bf16_f32 (16 insts vs 32 cvt + 32 insert):
//    ap[c] u32[k] = pk(pv[2c+(k>>1)][2(k&1)], pv[2c+(k>>1)][2(k&1)+1]).
// Uniform work, 512 blocks x 256 thr, 8 waves/CU. No-max softmax
// (Q pre-scaled by log2e/8). XCD map g=bid&7 -> bh [4g,4g+4).
// ---------------------------------------------------------------------------
__global__ __launch_bounds__(256, 2) void attn_kernel(
    const bf16_t* __restrict__ Q, const bf16_t* __restrict__ K,
    const bf16_t* __restrict__ VT, bf16_t* __restrict__ O) {
  __shared__ __align__(16) bf16_t Ks[2][128 * 64];  // K dbuf, 32 KB
  __shared__ __align__(16) bf16_t Vt[3][64 * 128];  // V tri-buf, 48 KB

  const int tid = threadIdx.x;
  const int w = tid >> 6, l = tid & 63;
  const int lq = l & 15, qd = l >> 4;
  const int bid = blockIdx.x;
  const int g = bid & 7, t = bid >> 3;  // 64 blocks per XCD-group
  const int bh = g * 4 + (t & 3);       // 4 bh per XCD-group: L2-resident K/VT
  const int p = t >> 2;                 // pair index: q-tiles {31-p, p}
  const int b = bh >> 4, h = bh & 15;
  const size_t rowbase = (size_t)b * S;
  const bf16_t* Kg = K + rowbase * E + h * 64;
  const bf16_t* Vg = VT + (size_t)bh * 64 * S;

  bf16x8 ones;
#pragma unroll
  for (int jj = 0; jj < 8; ++jj) ones[jj] = (bf16_t)1.0f;

  // prefetch 128-key tile 0 into K slot 0 / V slot 0
  stage_tile<128, 256>(Kg, E, Ks[0], tid);
  stage_v128(Vg, S, Vt[0], tid);
  int cb = 0, vcur = 0;

#pragma unroll 1
  for (int seg = 0; seg < 2; ++seg) {
    const int qt = seg ? p : 31 - p;    // heavy q-tile first
    const int T = (qt + 2) >> 1;        // 128-key tiles this segment
    const int qr = qt * 64 + w * 16;    // wave rows [qr, qr+16)
    const int qg = qr + lq;             // this lane's query row

    bf16x8 aq[2];
#pragma unroll
    for (int ks = 0; ks < 2; ++ks)
      aq[ks] = *(const bf16x8*)(Q + (rowbase + qr + lq) * E + h * 64 +
                                ks * 32 + qd * 8);

    f32x4 oacc[4];
#pragma unroll
    for (int nt = 0; nt < 4; ++nt) oacc[nt] = (f32x4){0.f, 0.f, 0.f, 0.f};
    f32x4 osum = (f32x4){0.f, 0.f, 0.f, 0.f};
    bf16x8 ap_prev[4];                   // P frags of tile kt-1 (128 keys)
    int vprev = vcur;

    // PV of the previous tile: 16 oacc-MFMA + 4 ones-MFMA
    auto do_pv = [&](const bf16_t* Vp) {
#pragma unroll
      for (int c = 0; c < 4; ++c) {
        bf16x8 bv[4];
#pragma unroll
        for (int nt = 0; nt < 4; ++nt)
          bv[nt] = read_v128(Vp, nt * 16 + lq, c * 4 + qd);
#pragma unroll
        for (int nt = 0; nt < 4; ++nt)
          oacc[nt] = MFMA16(ap_prev[c], bv[nt], oacc[nt]);
        osum = MFMA16(ap_prev[c], ones, osum);
      }
    };

    for (int kt = 0; kt < T; ++kt) {
      __syncthreads();  // drains DMA into K[cb]/V[vcur]; all waves' reads of
                        // the slots being rewritten completed last iteration
      const int vnext = (vcur + 1 == 3) ? 0 : vcur + 1;
      if (kt < T - 1) {
        const int kn = (kt + 1) * 128;
        stage_tile<128, 256>(Kg + (size_t)kn * E, E, Ks[cb ^ 1], tid);
        stage_v128(Vg + kn, S, Vt[vnext], tid);
      } else if (seg == 0) {      // last A-iter: prefetch segment B's tile 0
        stage_tile<128, 256>(Kg, E, Ks[cb ^ 1], tid);
        stage_v128(Vg, S, Vt[vnext], tid);
      }
      const bf16_t* Kc = Ks[cb];
      const int k0 = kt * 128;
      const bool needmask = (kt == T - 1);

      // ---- S^T = K * Q^T : 16 MFMA; lane holds q=lq, keys nt*16+qd*4+r ----
      f32x4 sacc[8];
#pragma unroll
      for (int nt = 0; nt < 8; ++nt) sacc[nt] = (f32x4){0.f, 0.f, 0.f, 0.f};
      __builtin_amdgcn_s_setprio(1);
#pragma unroll
      for (int ks = 0; ks < 2; ++ks) {
        bf16x8 bk[8];
#pragma unroll
        for (int nt = 0; nt < 8; ++nt)
          bk[nt] = read_frag(Kc, nt * 16 + lq, ks * 4 + qd);
#pragma unroll
        for (int nt = 0; nt < 8; ++nt)
          sacc[nt] = MFMA16(bk[nt], aq[ks], sacc[nt]);
      }
      // ---- PV of tile kt-1 (independent; overlaps softmax below) ----
      if (kt > 0) do_pv(Vt[vprev]);
      __builtin_amdgcn_s_setprio(0);

      // ---- softmax: exp2 in f32 (mask on f32), pack via v_cvt_pk_bf16_f32 ----
      float pvf[8][4];
      if (needmask) {
#pragma unroll
        for (int nt = 0; nt < 8; ++nt)
#pragma unroll
          for (int r = 0; r < 4; ++r) {
            float pv = __builtin_amdgcn_exp2f(sacc[nt][r]);
            const int kg = k0 + nt * 16 + qd * 4 + r;
            pvf[nt][r] = (kg > qg) ? 0.f : pv;
          }
      } else {
#pragma unroll
        for (int nt = 0; nt < 8; ++nt)
#pragma unroll
          for (int r = 0; r < 4; ++r)
            pvf[nt][r] = __builtin_amdgcn_exp2f(sacc[nt][r]);
      }
#pragma unroll
      for (int c = 0; c < 4; ++c) {
        union { unsigned u[4]; bf16x8 v; } pk;
        pk.u[0] = cvtpk(pvf[2 * c][0], pvf[2 * c][1]);
        pk.u[1] = cvtpk(pvf[2 * c][2], pvf[2 * c][3]);
        pk.u[2] = cvtpk(pvf[2 * c + 1][0], pvf[2 * c + 1][1]);
        pk.u[3] = cvtpk(pvf[2 * c + 1][2], pvf[2 * c + 1][3]);
        ap_prev[c] = pk.v;
      }
      vprev = vcur;
      vcur = vnext;
      cb ^= 1;
    }
    // epilogue: PV of the segment's last tile
    do_pv(Vt[vprev]);

    // normalize + store: osum[r] = rowsum for q-row qd*4+r = C-layout rows
    float rinv[4];
#pragma unroll
    for (int r = 0; r < 4; ++r) rinv[r] = 1.0f / osum[r];
#pragma unroll
    for (int nt = 0; nt < 4; ++nt)
#pragma unroll
      for (int r = 0; r < 4; ++r) {
        const int qgw = qr + qd * 4 + r;
        O[(rowbase + qgw) * E + h * 64 + nt * 16 + lq] =
            (bf16_t)(oacc[nt][r] * rinv[r]);
      }
  }
}

// ---------------------------------------------------------------------------
// launch
// ---------------------------------------------------------------------------
extern "C" void kernel_launch(void* const* d_in, const int* in_sizes, int n_in,
                              void* d_out, int out_size, void* d_ws, size_t ws_size,
                              hipStream_t stream) {
  const float* x  = (const float*)d_in[0];
  const float* Wq = (const float*)d_in[1];
  const float* bq = (const float*)d_in[2];
  const float* Wk = (const float*)d_in[3];
  const float* bk = (const float*)d_in[4];
  const float* Wv = (const float*)d_in[5];
  const float* bv = (const float*)d_in[6];
  const float* Wo = (const float*)d_in[7];
  const float* bo = (const float*)d_in[8];
  float* out = (float*)d_out;

  unsigned char* ws = (unsigned char*)d_ws;
  constexpr size_t MB = 1ull << 20;
  bf16_t* xb  = (bf16_t*)(ws + 0 * MB);   // 8 MB; reused as Ob after qkv
  bf16_t* wqb = (bf16_t*)(ws + 8 * MB);   // wq/wk/wv contiguous [3072][1024]
  bf16_t* wkb = (bf16_t*)(ws + 10 * MB);
  bf16_t* wvb = (bf16_t*)(ws + 12 * MB);
  bf16_t* wob = (bf16_t*)(ws + 14 * MB);
  bf16_t* Qb  = (bf16_t*)(ws + 16 * MB);  // Q/K contiguous [2][4096][1024]
  bf16_t* VT  = (bf16_t*)(ws + 40 * MB);  // [32 bh][64 d][2048 s, sigma-perm per 64]
  bf16_t* Ob  = xb;                       // xb dead after qkv

  cvt_all_kernel<<<4096, 256, 0, stream>>>(
      x, Wq, Wk, Wv, Wo, xb, wqb, wkb, wvb, wob);

  qkv8_kernel<<<256, 512, 0, stream>>>(xb, wqb, bq, bk, bv, Qb, VT);

  attn_kernel<<<512, 256, 0, stream>>>(Qb, Qb + (size_t)M * E, VT, Ob);

  oproj_gemm_kernel<<<512, 256, 0, stream>>>(Ob, wob, bo, out);
}